// Round 5
// baseline (388.033 us; speedup 1.0000x reference)
//
#include <hip/hip_runtime.h>

#define KK 12
#define LL 4096
#define DD 128
#define NN 16
#define RR 8
#define NC 64
#define LC 64
#define XST 132            // x-tile LDS stride (floats)
#define SDST 44            // x_dbl LDS row stride (floats)
#define XDBL_TILE (64 * SDST)   // 2816 floats per (k,chunk) tile

__device__ __forceinline__ int pos_of(int k, int l) {
    int o = k >> 1;
    int le = (k & 1) ? (4095 - l) : l;
    int t1 = le >> 8, t2 = (le >> 4) & 15, t3 = le & 15;
    switch (o) {
        case 0:  return (t1 << 8) | (t2 << 4) | t3;
        case 1:  return (t1 << 8) | (t3 << 4) | t2;
        case 2:  return (t3 << 8) | (t2 << 4) | t1;
        case 3:  return (t2 << 8) | (t3 << 4) | t1;
        case 4:  return (t2 << 8) | (t1 << 4) | t3;
        default: return (t3 << 8) | (t1 << 4) | t2;
    }
}

__device__ __forceinline__ float delta_row_z(const float* sdbl, int i,
                                             float4 w0, float4 w1, float bz) {
    const float4* dr = (const float4*)(sdbl + i * SDST);
    float4 r0 = dr[0], r1 = dr[1];
    return bz + w0.x * r0.x + w0.y * r0.y + w0.z * r0.z + w0.w * r0.w
              + w1.x * r1.x + w1.y * r1.y + w1.z * r1.z + w1.w * r1.w;
}

__device__ __forceinline__ bool load_A8(const float* __restrict__ A_logs,
                                        int k, int d, int n0, float* A8, float& A0) {
    const float4* ap = (const float4*)(A_logs + ((size_t)(k * DD + d) * NN + n0));
    float4 a0 = ap[0], a1 = ap[1];
    A8[0] = -__expf(a0.x); A8[1] = -__expf(a0.y);
    A8[2] = -__expf(a0.z); A8[3] = -__expf(a0.w);
    A8[4] = -__expf(a1.x); A8[5] = -__expf(a1.y);
    A8[6] = -__expf(a1.z); A8[7] = -__expf(a1.w);
    A0 = -__expf(A_logs[(size_t)(k * DD + d) * NN]);
    bool s = true;
    #pragma unroll
    for (int j = 0; j < 8; j++) {
        float m = (float)(n0 + j + 1);
        s = s && (fabsf(A8[j] - m * A0) <= 1e-4f * m * fabsf(A0));
    }
    return s;
}

// powers e[j] = base^(n0+j+1) from q, or generic exps of (v * A8[j])
template<bool S>
__device__ __forceinline__ void e8_from(float v, float A0, const float* A8,
                                        int half, float* e) {
    if (S) {
        float q = __expf(v * A0);
        float q2 = q * q, q4 = q2 * q2, q8 = q4 * q4;
        e[0] = half ? q8 * q : q;
        #pragma unroll
        for (int j = 1; j < 8; j++) e[j] = e[j - 1] * q;
    } else {
        #pragma unroll
        for (int j = 0; j < 8; j++) e[j] = __expf(v * A8[j]);
    }
}

// ---------------------------------------------------------------------------
// K1 scan body (template over structured-A). Thread = (d, half); y buffered
// in registers: thread (d,half) owns i in [32*half, 32*half+32).
// ---------------------------------------------------------------------------
template<bool S>
__device__ __forceinline__ void scanA_body(
    const float* xs, const float* sdbl, int k, int c, int l0,
    int d, int half, int n0, const float* A8, float A0,
    float4 w0, float4 w1, float bz, float Dval,
    float* __restrict__ S_g, float* __restrict__ dtsum,
    float* __restrict__ oy)
{
    float h[8] = {0, 0, 0, 0, 0, 0, 0, 0};
    float ybr[32];
    float dsum = 0.0f;

    #pragma unroll
    for (int i = 0; i < LC; i++) {
        float z = delta_row_z(sdbl, i, w0, w1, bz);
        float E = __expf(-fabsf(z));
        float dt = fmaxf(z, 0.0f) + __logf(1.0f + E);
        float u = xs[i * XST + d];
        dsum += dt;
        float tu = dt * u;
        float e[8];
        e8_from<S>(dt, A0, A8, half, e);
        const float4* bp = (const float4*)(&sdbl[i * SDST + 8 + n0]);
        float4 b0 = bp[0], b1 = bp[1];
        const float4* cp = (const float4*)(&sdbl[i * SDST + 24 + n0]);
        float4 c0 = cp[0], c1 = cp[1];
        h[0] = e[0] * h[0] + tu * b0.x;  h[1] = e[1] * h[1] + tu * b0.y;
        h[2] = e[2] * h[2] + tu * b0.z;  h[3] = e[3] * h[3] + tu * b0.w;
        h[4] = e[4] * h[4] + tu * b1.x;  h[5] = e[5] * h[5] + tu * b1.y;
        h[6] = e[6] * h[6] + tu * b1.z;  h[7] = e[7] * h[7] + tu * b1.w;
        float yp = h[0] * c0.x + h[1] * c0.y + h[2] * c0.z + h[3] * c0.w
                 + h[4] * c1.x + h[5] * c1.y + h[6] * c1.z + h[7] * c1.w;
        float yv = yp + __shfl_xor(yp, 1) + Dval * u;
        if ((i >> 5) == half) ybr[i & 31] = yv;
    }

    // chunk end-state + dtsum
    float4* sp = (float4*)(S_g + (((size_t)(k * NC + c) * DD + d) * NN + n0));
    sp[0] = make_float4(h[0], h[1], h[2], h[3]);
    sp[1] = make_float4(h[4], h[5], h[6], h[7]);
    if (!half) dtsum[(k * NC + c) * DD + d] = dsum;

    // y store: 8 x dwordx4 per thread (L2 merges 16B granules per 64B line)
    float* base = oy + ((size_t)(k * DD + d)) * LL + l0 + half * 32;
    #pragma unroll
    for (int j = 0; j < 8; j++)
        *(float4*)(base + j * 4) = make_float4(ybr[4*j], ybr[4*j+1],
                                               ybr[4*j+2], ybr[4*j+3]);
}

// ---------------------------------------------------------------------------
// K1: proj GEMM + phase A local scan. Block = (k, chunk), 256 threads.
// ---------------------------------------------------------------------------
__global__ __launch_bounds__(256, 3) void k1_proj_scanA(
    const float* __restrict__ x, const float* __restrict__ Wp,
    const float* __restrict__ Wdt, const float* __restrict__ bias,
    const float* __restrict__ A_logs, const float* __restrict__ Ds,
    float* __restrict__ S_g, float* __restrict__ dtsum,
    float* __restrict__ oy, float* __restrict__ xdbl)
{
    const int blk = blockIdx.x;
    const int k = blk >> 6;
    const int c = blk & 63;
    const int l0 = c * LC;
    const int t = threadIdx.x;

    __shared__ __align__(16) float xs[64 * XST];    // x-tile [l][d], intact all kernel
    __shared__ __align__(16) float sdbl[64 * SDST]; // x_dbl [l][c]: 0-7 dts, 8-23 B, 24-39 C
    __shared__ int pos_s[64];

    if (t < 64) pos_s[t] = pos_of(k, l0 + t);
    __syncthreads();

    // ---- stage x tile (coalesced) ----
    {
        int lane32 = t & 31, rowi = t >> 5;
        #pragma unroll
        for (int p = 0; p < 8; p++) {
            int l = p * 8 + rowi;
            float4 v = *(const float4*)(x + (size_t)pos_s[l] * DD + lane32 * 4);
            *(float4*)(&xs[l * XST + lane32 * 4]) = v;
        }
    }
    __syncthreads();

    // ---- projection GEMM: wave cg computes 10 of 40 channels ----
    {
        int l = t & 63, cgch = t >> 6;
        float acc[10];
        #pragma unroll
        for (int j = 0; j < 10; j++) acc[j] = 0.0f;
        const float* wk = Wp + (size_t)(k * 40 + cgch * 10) * DD;
        for (int d4 = 0; d4 < DD; d4 += 4) {
            float4 xv = *(const float4*)(&xs[l * XST + d4]);
            #pragma unroll
            for (int j = 0; j < 10; j++) {
                const float* w = wk + j * DD + d4;   // wave-uniform -> s_load
                acc[j] += xv.x * w[0] + xv.y * w[1] + xv.z * w[2] + xv.w * w[3];
            }
        }
        #pragma unroll
        for (int j = 0; j < 10; j++) sdbl[l * SDST + cgch * 10 + j] = acc[j];
    }
    __syncthreads();

    // ---- spill x_dbl tile for K3 (chunk 0 never needs correction) ----
    if (c != 0) {
        const float4* s4 = (const float4*)sdbl;
        float4* g4 = (float4*)(xdbl + (size_t)blk * XDBL_TILE);
        for (int idx = t; idx < XDBL_TILE / 4; idx += 256) g4[idx] = s4[idx];
    }

    // ---- phase A scan ----
    const int d = t >> 1, half = t & 1, n0 = half * 8;
    float A8[8], A0;
    bool structured = load_A8(A_logs, k, d, n0, A8, A0);
    const float4* wp4 = (const float4*)(Wdt + (size_t)(k * DD + d) * RR);
    const float4 w0 = wp4[0], w1 = wp4[1];
    const float bz = bias[k * DD + d];
    const float Dval = Ds[k * DD + d];

    if (structured)
        scanA_body<true>(xs, sdbl, k, c, l0, d, half, n0, A8, A0, w0, w1, bz,
                         Dval, S_g, dtsum, oy);
    else
        scanA_body<false>(xs, sdbl, k, c, l0, d, half, n0, A8, A0, w0, w1, bz,
                          Dval, S_g, dtsum, oy);
}

// ---------------------------------------------------------------------------
// K2: sequential combine across chunks; S <- true initial state, in place.
// ---------------------------------------------------------------------------
__global__ __launch_bounds__(256) void k2_combine(
    float* __restrict__ S_g, const float* __restrict__ dtsum,
    const float* __restrict__ A_logs)
{
    int tid = blockIdx.x * 256 + threadIdx.x;   // k*2048 + d*16 + n
    int kk = tid >> 11, rem = tid & 2047, dd2 = rem >> 4;
    float Ac = -__expf(A_logs[tid]);
    float hh = 0.0f;
    #pragma unroll 8
    for (int c2 = 0; c2 < NC; c2++) {
        size_t base = ((size_t)(kk * NC + c2)) * 2048 + rem;
        float s = S_g[base];
        float dsv = dtsum[(kk * NC + c2) * DD + dd2];
        S_g[base] = hh;
        hh = s + __expf(dsv * Ac) * hh;
    }
}

// ---------------------------------------------------------------------------
// K3 correction body: y(l) += C(l) . (exp(Dsum_l * A) (.) h0), Dsum = prefix
// sum of dt. Serial chain is ONE add per step.
// ---------------------------------------------------------------------------
template<bool S>
__device__ __forceinline__ void corr_body(
    const float* sdbl, int k, int c, int l0, int d, int half, int n0,
    const float* A8, float A0, const float* h0,
    float4 w0, float4 w1, float bz, float* __restrict__ oy)
{
    float ybr[32];
    float Dsum = 0.0f;

    #pragma unroll
    for (int i = 0; i < LC; i++) {
        float z = delta_row_z(sdbl, i, w0, w1, bz);
        float E = __expf(-fabsf(z));
        float dt = fmaxf(z, 0.0f) + __logf(1.0f + E);
        Dsum += dt;
        float e[8];
        e8_from<S>(Dsum, A0, A8, half, e);
        const float4* cp = (const float4*)(&sdbl[i * SDST + 24 + n0]);
        float4 c0 = cp[0], c1 = cp[1];
        float yp = e[0]*h0[0]*c0.x + e[1]*h0[1]*c0.y + e[2]*h0[2]*c0.z + e[3]*h0[3]*c0.w
                 + e[4]*h0[4]*c1.x + e[5]*h0[5]*c1.y + e[6]*h0[6]*c1.z + e[7]*h0[7]*c1.w;
        float yv = yp + __shfl_xor(yp, 1);
        if ((i >> 5) == half) ybr[i & 31] = yv;
    }

    float* base = oy + ((size_t)(k * DD + d)) * LL + l0 + half * 32;
    #pragma unroll
    for (int j = 0; j < 8; j++) {
        float4 v = *(float4*)(base + j * 4);
        v.x += ybr[4*j]; v.y += ybr[4*j+1]; v.z += ybr[4*j+2]; v.w += ybr[4*j+3];
        *(float4*)(base + j * 4) = v;
    }
}

__global__ __launch_bounds__(256, 4) void k3_corr(
    const float* __restrict__ Wdt, const float* __restrict__ bias,
    const float* __restrict__ A_logs, const float* __restrict__ S_g,
    const float* __restrict__ xdbl, float* __restrict__ oy)
{
    const int blk = blockIdx.x;
    const int k = blk >> 6;
    const int c = blk & 63;
    if (c == 0) return;                 // chunk 0 has h0 = 0
    const int l0 = c * LC;
    const int t = threadIdx.x;

    __shared__ __align__(16) float sdbl[64 * SDST];
    {
        const float4* g4 = (const float4*)(xdbl + (size_t)blk * XDBL_TILE);
        float4* s4 = (float4*)sdbl;
        for (int idx = t; idx < XDBL_TILE / 4; idx += 256) s4[idx] = g4[idx];
    }
    __syncthreads();

    const int d = t >> 1, half = t & 1, n0 = half * 8;
    float A8[8], A0;
    bool structured = load_A8(A_logs, k, d, n0, A8, A0);
    const float4* wp4 = (const float4*)(Wdt + (size_t)(k * DD + d) * RR);
    const float4 w0 = wp4[0], w1 = wp4[1];
    const float bz = bias[k * DD + d];

    float h0[8];
    {
        const float4* hp = (const float4*)(S_g + (((size_t)(k * NC + c) * DD + d) * NN + n0));
        float4 h40 = hp[0], h41 = hp[1];
        h0[0] = h40.x; h0[1] = h40.y; h0[2] = h40.z; h0[3] = h40.w;
        h0[4] = h41.x; h0[5] = h41.y; h0[6] = h41.z; h0[7] = h41.w;
    }

    if (structured)
        corr_body<true>(sdbl, k, c, l0, d, half, n0, A8, A0, h0, w0, w1, bz, oy);
    else
        corr_body<false>(sdbl, k, c, l0, d, half, n0, A8, A0, h0, w0, w1, bz, oy);
}

// ---------------------------------------------------------------------------
// K4: restore + merge (reference's (D,L)-flat reshape semantics).
// ---------------------------------------------------------------------------
__global__ __launch_bounds__(256) void k4_merge(
    const float* __restrict__ out_y, const float* __restrict__ mw,
    const float* __restrict__ mb, float* __restrict__ out)
{
    int idx = blockIdx.x * 256 + threadIdx.x;
    int dd = idx & 127;
    int p = idx >> 7;
    int i3 = p & 15, i2 = (p >> 4) & 15, i1 = (p >> 8) & 15;

    float accv = mb[0];
    #pragma unroll
    for (int k = 0; k < 12; k++) {
        int a1 = i1, a2 = i2, a3 = i3;
        if (k & 1) { a1 = 15 - i1; a2 = 15 - i2; a3 = 15 - i3; }
        int j1, j2, j3;
        switch (k >> 1) {
            case 0:  j1 = a1; j2 = a2; j3 = a3; break;
            case 1:  j1 = a1; j2 = a3; j3 = a2; break;
            case 2:  j1 = a3; j2 = a2; j3 = a1; break;
            case 3:  j1 = a3; j2 = a1; j3 = a2; break;
            case 4:  j1 = a2; j2 = a1; j3 = a3; break;
            default: j1 = a2; j2 = a3; j3 = a1; break;
        }
        int jb = (j1 << 8) | (j2 << 4) | j3;
        accv += mw[k] * out_y[(size_t)k * (DD * LL) + (jb >> 5) * LL
                              + ((jb & 31) << 7) + dd];
    }
    out[idx] = accv;
}

extern "C" void kernel_launch(void* const* d_in, const int* in_sizes, int n_in,
                              void* d_out, int out_size, void* d_ws, size_t ws_size,
                              hipStream_t stream) {
    const float* x      = (const float*)d_in[0];
    const float* Wp     = (const float*)d_in[1];
    const float* Wdt    = (const float*)d_in[2];
    const float* bias   = (const float*)d_in[3];
    const float* A_logs = (const float*)d_in[4];
    const float* Ds     = (const float*)d_in[5];
    const float* mw     = (const float*)d_in[6];
    const float* mb     = (const float*)d_in[7];
    float* out = (float*)d_out;

    float* ws   = (float*)d_ws;
    float* S_g  = ws;                                 // K*NC*D*N = 1572864
    float* dts  = S_g + (size_t)KK * NC * DD * NN;    // K*NC*D   =   98304
    float* oy   = dts + (size_t)KK * NC * DD;         // K*D*L    = 6291456
    float* xdbl = oy + (size_t)KK * DD * LL;          // 768*2816 = 2162688

    k1_proj_scanA<<<dim3(KK * NC), dim3(256), 0, stream>>>(
        x, Wp, Wdt, bias, A_logs, Ds, S_g, dts, oy, xdbl);
    k2_combine<<<dim3(KK * DD * NN / 256), dim3(256), 0, stream>>>(S_g, dts, A_logs);
    k3_corr<<<dim3(KK * NC), dim3(256), 0, stream>>>(Wdt, bias, A_logs, S_g, xdbl, oy);
    k4_merge<<<dim3(LL * DD / 256), dim3(256), 0, stream>>>(oy, mw, mb, out);
}

// Round 6
// 174.811 us; speedup vs baseline: 2.2197x; 2.2197x over previous
//
#include <hip/hip_runtime.h>

#define KK 12
#define LL 4096
#define DD 128
#define NN 16
#define RR 8
#define NC 64
#define LC 64
#define XST 132            // x-tile / ybuf LDS stride (floats)
#define SDST 44            // x_dbl LDS row stride (floats)
#define XDBL_TILE (64 * SDST)   // 2816 floats per (k,chunk) tile

__device__ __forceinline__ int pos_of(int k, int l) {
    int o = k >> 1;
    int le = (k & 1) ? (4095 - l) : l;
    int t1 = le >> 8, t2 = (le >> 4) & 15, t3 = le & 15;
    switch (o) {
        case 0:  return (t1 << 8) | (t2 << 4) | t3;
        case 1:  return (t1 << 8) | (t3 << 4) | t2;
        case 2:  return (t3 << 8) | (t2 << 4) | t1;
        case 3:  return (t2 << 8) | (t3 << 4) | t1;
        case 4:  return (t2 << 8) | (t1 << 4) | t3;
        default: return (t3 << 8) | (t1 << 4) | t2;
    }
}

__device__ __forceinline__ float delta_row_z(const float* sdbl, int i,
                                             float4 w0, float4 w1, float bz) {
    const float4* dr = (const float4*)(sdbl + i * SDST);
    float4 r0 = dr[0], r1 = dr[1];
    return bz + w0.x * r0.x + w0.y * r0.y + w0.z * r0.z + w0.w * r0.w
              + w1.x * r1.x + w1.y * r1.y + w1.z * r1.z + w1.w * r1.w;
}

__device__ __forceinline__ bool load_A8(const float* __restrict__ A_logs,
                                        int k, int d, int n0, float* A8, float& A0) {
    const float4* ap = (const float4*)(A_logs + ((size_t)(k * DD + d) * NN + n0));
    float4 a0 = ap[0], a1 = ap[1];
    A8[0] = -__expf(a0.x); A8[1] = -__expf(a0.y);
    A8[2] = -__expf(a0.z); A8[3] = -__expf(a0.w);
    A8[4] = -__expf(a1.x); A8[5] = -__expf(a1.y);
    A8[6] = -__expf(a1.z); A8[7] = -__expf(a1.w);
    A0 = -__expf(A_logs[(size_t)(k * DD + d) * NN]);
    bool s = true;
    #pragma unroll
    for (int j = 0; j < 8; j++) {
        float m = (float)(n0 + j + 1);
        s = s && (fabsf(A8[j] - m * A0) <= 1e-4f * m * fabsf(A0));
    }
    return s;
}

// powers e[j] = base^(n0+j+1) from q = exp(v*A0), or generic exps of v*A8[j]
template<bool S>
__device__ __forceinline__ void e8_from(float v, float A0, const float* A8,
                                        int half, float* e) {
    if (S) {
        float q = __expf(v * A0);
        float q2 = q * q, q4 = q2 * q2, q8 = q4 * q4;
        e[0] = half ? q8 * q : q;
        #pragma unroll
        for (int j = 1; j < 8; j++) e[j] = e[j - 1] * q;
    } else {
        #pragma unroll
        for (int j = 0; j < 8; j++) e[j] = __expf(v * A8[j]);
    }
}

// ---------------------------------------------------------------------------
// K1 scan body. Thread = (d, half). u read from xs[i][d]; y written back into
// the same LDS word after consumption (own-d only -> race-free; no conflicts).
// ---------------------------------------------------------------------------
template<bool S>
__device__ __forceinline__ void scanA_body(
    float* xs, const float* sdbl, int k, int c,
    int d, int half, int n0, const float* A8, float A0,
    float4 w0, float4 w1, float bz, float Dval,
    float* __restrict__ S_g, float* __restrict__ dtsum)
{
    float h[8] = {0, 0, 0, 0, 0, 0, 0, 0};
    float dsum = 0.0f;

    #pragma unroll 4
    for (int i = 0; i < LC; i++) {
        float z = delta_row_z(sdbl, i, w0, w1, bz);
        float E = __expf(-fabsf(z));
        float dt = fmaxf(z, 0.0f) + __logf(1.0f + E);
        float u = xs[i * XST + d];
        dsum += dt;
        float tu = dt * u;
        float e[8];
        e8_from<S>(dt, A0, A8, half, e);
        const float4* bp = (const float4*)(&sdbl[i * SDST + 8 + n0]);
        float4 b0 = bp[0], b1 = bp[1];
        const float4* cp = (const float4*)(&sdbl[i * SDST + 24 + n0]);
        float4 c0 = cp[0], c1 = cp[1];
        h[0] = e[0] * h[0] + tu * b0.x;  h[1] = e[1] * h[1] + tu * b0.y;
        h[2] = e[2] * h[2] + tu * b0.z;  h[3] = e[3] * h[3] + tu * b0.w;
        h[4] = e[4] * h[4] + tu * b1.x;  h[5] = e[5] * h[5] + tu * b1.y;
        h[6] = e[6] * h[6] + tu * b1.z;  h[7] = e[7] * h[7] + tu * b1.w;
        float yp = h[0] * c0.x + h[1] * c0.y + h[2] * c0.z + h[3] * c0.w
                 + h[4] * c1.x + h[5] * c1.y + h[6] * c1.z + h[7] * c1.w;
        float yv = yp + __shfl_xor(yp, 1) + Dval * u;
        if (!half) xs[i * XST + d] = yv;    // overwrite consumed u slot
    }

    float4* sp = (float4*)(S_g + (((size_t)(k * NC + c) * DD + d) * NN + n0));
    sp[0] = make_float4(h[0], h[1], h[2], h[3]);
    sp[1] = make_float4(h[4], h[5], h[6], h[7]);
    if (!half) dtsum[(k * NC + c) * DD + d] = dsum;
}

// ---------------------------------------------------------------------------
// K1: proj GEMM + phase A local scan. Block = (k, chunk), 256 threads.
// ---------------------------------------------------------------------------
__global__ __launch_bounds__(256, 3) void k1_proj_scanA(
    const float* __restrict__ x, const float* __restrict__ Wp,
    const float* __restrict__ Wdt, const float* __restrict__ bias,
    const float* __restrict__ A_logs, const float* __restrict__ Ds,
    float* __restrict__ S_g, float* __restrict__ dtsum,
    float* __restrict__ oy, float* __restrict__ xdbl)
{
    const int blk = blockIdx.x;
    const int k = blk >> 6;
    const int c = blk & 63;
    const int l0 = c * LC;
    const int t = threadIdx.x;

    __shared__ __align__(16) float xs[64 * XST];    // x-tile [l][d]; becomes ybuf [l][d]
    __shared__ __align__(16) float sdbl[64 * SDST]; // x_dbl [l][c]: 0-7 dts, 8-23 B, 24-39 C
    __shared__ int pos_s[64];

    if (t < 64) pos_s[t] = pos_of(k, l0 + t);
    __syncthreads();

    // ---- stage x tile (coalesced) ----
    {
        int lane32 = t & 31, rowi = t >> 5;
        #pragma unroll
        for (int p = 0; p < 8; p++) {
            int l = p * 8 + rowi;
            float4 v = *(const float4*)(x + (size_t)pos_s[l] * DD + lane32 * 4);
            *(float4*)(&xs[l * XST + lane32 * 4]) = v;
        }
    }
    __syncthreads();

    // ---- projection GEMM: wave cg computes 10 of 40 channels ----
    {
        int l = t & 63, cgch = t >> 6;
        float acc[10];
        #pragma unroll
        for (int j = 0; j < 10; j++) acc[j] = 0.0f;
        const float* wk = Wp + (size_t)(k * 40 + cgch * 10) * DD;
        for (int d4 = 0; d4 < DD; d4 += 4) {
            float4 xv = *(const float4*)(&xs[l * XST + d4]);
            #pragma unroll
            for (int j = 0; j < 10; j++) {
                const float* w = wk + j * DD + d4;   // wave-uniform -> s_load
                acc[j] += xv.x * w[0] + xv.y * w[1] + xv.z * w[2] + xv.w * w[3];
            }
        }
        #pragma unroll
        for (int j = 0; j < 10; j++) sdbl[l * SDST + cgch * 10 + j] = acc[j];
    }
    __syncthreads();

    // ---- spill x_dbl tile for K3 (chunk 0 never needs correction) ----
    if (c != 0) {
        const float4* s4 = (const float4*)sdbl;
        float4* g4 = (float4*)(xdbl + (size_t)blk * XDBL_TILE);
        for (int idx = t; idx < XDBL_TILE / 4; idx += 256) g4[idx] = s4[idx];
    }

    // ---- phase A scan ----
    const int d = t >> 1, half = t & 1, n0 = half * 8;
    float A8[8], A0;
    bool structured = load_A8(A_logs, k, d, n0, A8, A0);
    const float4* wp4 = (const float4*)(Wdt + (size_t)(k * DD + d) * RR);
    const float4 w0 = wp4[0], w1 = wp4[1];
    const float bz = bias[k * DD + d];
    const float Dval = Ds[k * DD + d];

    if (structured)
        scanA_body<true>(xs, sdbl, k, c, d, half, n0, A8, A0, w0, w1, bz,
                         Dval, S_g, dtsum);
    else
        scanA_body<false>(xs, sdbl, k, c, d, half, n0, A8, A0, w0, w1, bz,
                          Dval, S_g, dtsum);
    __syncthreads();

    // ---- transposed y store: oy[k][d][l0 + half*32 + j] ----
    {
        float* base = oy + ((size_t)(k * DD + d)) * LL + l0 + half * 32;
        #pragma unroll
        for (int p = 0; p < 8; p++) {
            int j = p * 4;
            float4 v = make_float4(xs[(half * 32 + j + 0) * XST + d],
                                   xs[(half * 32 + j + 1) * XST + d],
                                   xs[(half * 32 + j + 2) * XST + d],
                                   xs[(half * 32 + j + 3) * XST + d]);
            *(float4*)(base + j) = v;
        }
    }
}

// ---------------------------------------------------------------------------
// K2: sequential combine across chunks; S <- true initial state, in place.
// ---------------------------------------------------------------------------
__global__ __launch_bounds__(256) void k2_combine(
    float* __restrict__ S_g, const float* __restrict__ dtsum,
    const float* __restrict__ A_logs)
{
    int tid = blockIdx.x * 256 + threadIdx.x;   // k*2048 + d*16 + n
    int kk = tid >> 11, rem = tid & 2047, dd2 = rem >> 4;
    float Ac = -__expf(A_logs[tid]);
    float hh = 0.0f;
    #pragma unroll 8
    for (int c2 = 0; c2 < NC; c2++) {
        size_t base = ((size_t)(kk * NC + c2)) * 2048 + rem;
        float s = S_g[base];
        float dsv = dtsum[(kk * NC + c2) * DD + dd2];
        S_g[base] = hh;
        hh = s + __expf(dsv * Ac) * hh;
    }
}

// ---------------------------------------------------------------------------
// K3 body: y(l) += C(l) . (exp(Dsum_l * A) (.) h0). Serial chain = 1 add.
// y into LDS ybuf[l][d] (conflict-free), then coalesced RMW of oy.
// ---------------------------------------------------------------------------
template<bool S>
__device__ __forceinline__ void corr_body(
    float* ybuf, const float* sdbl, int d, int half, int n0,
    const float* A8, float A0, const float* h0, float4 w0, float4 w1, float bz)
{
    float Dsum = 0.0f;
    #pragma unroll 4
    for (int i = 0; i < LC; i++) {
        float z = delta_row_z(sdbl, i, w0, w1, bz);
        float E = __expf(-fabsf(z));
        float dt = fmaxf(z, 0.0f) + __logf(1.0f + E);
        Dsum += dt;
        float e[8];
        e8_from<S>(Dsum, A0, A8, half, e);
        const float4* cp = (const float4*)(&sdbl[i * SDST + 24 + n0]);
        float4 c0 = cp[0], c1 = cp[1];
        float yp = e[0]*h0[0]*c0.x + e[1]*h0[1]*c0.y + e[2]*h0[2]*c0.z + e[3]*h0[3]*c0.w
                 + e[4]*h0[4]*c1.x + e[5]*h0[5]*c1.y + e[6]*h0[6]*c1.z + e[7]*h0[7]*c1.w;
        float yv = yp + __shfl_xor(yp, 1);
        if (!half) ybuf[i * XST + d] = yv;
    }
}

__global__ __launch_bounds__(256, 3) void k3_corr(
    const float* __restrict__ Wdt, const float* __restrict__ bias,
    const float* __restrict__ A_logs, const float* __restrict__ S_g,
    const float* __restrict__ xdbl, float* __restrict__ oy)
{
    const int blk = blockIdx.x;
    const int k = blk >> 6;
    const int c = blk & 63;
    if (c == 0) return;                 // chunk 0 has h0 = 0
    const int l0 = c * LC;
    const int t = threadIdx.x;

    __shared__ __align__(16) float sdbl[64 * SDST];
    __shared__ __align__(16) float ybuf[64 * XST];
    {
        const float4* g4 = (const float4*)(xdbl + (size_t)blk * XDBL_TILE);
        float4* s4 = (float4*)sdbl;
        for (int idx = t; idx < XDBL_TILE / 4; idx += 256) s4[idx] = g4[idx];
    }
    __syncthreads();

    const int d = t >> 1, half = t & 1, n0 = half * 8;
    float A8[8], A0;
    bool structured = load_A8(A_logs, k, d, n0, A8, A0);
    const float4* wp4 = (const float4*)(Wdt + (size_t)(k * DD + d) * RR);
    const float4 w0 = wp4[0], w1 = wp4[1];
    const float bz = bias[k * DD + d];

    float h0[8];
    {
        const float4* hp = (const float4*)(S_g + (((size_t)(k * NC + c) * DD + d) * NN + n0));
        float4 h40 = hp[0], h41 = hp[1];
        h0[0] = h40.x; h0[1] = h40.y; h0[2] = h40.z; h0[3] = h40.w;
        h0[4] = h41.x; h0[5] = h41.y; h0[6] = h41.z; h0[7] = h41.w;
    }

    if (structured)
        corr_body<true>(ybuf, sdbl, d, half, n0, A8, A0, h0, w0, w1, bz);
    else
        corr_body<false>(ybuf, sdbl, d, half, n0, A8, A0, h0, w0, w1, bz);
    __syncthreads();

    // ---- transposed RMW of oy tile ----
    {
        float* base = oy + ((size_t)(k * DD + d)) * LL + l0 + half * 32;
        #pragma unroll
        for (int p = 0; p < 8; p++) {
            int j = p * 4;
            float4 v = *(float4*)(base + j);
            v.x += ybuf[(half * 32 + j + 0) * XST + d];
            v.y += ybuf[(half * 32 + j + 1) * XST + d];
            v.z += ybuf[(half * 32 + j + 2) * XST + d];
            v.w += ybuf[(half * 32 + j + 3) * XST + d];
            *(float4*)(base + j) = v;
        }
    }
}

// ---------------------------------------------------------------------------
// K4: restore + merge (reference's (D,L)-flat reshape semantics).
// ---------------------------------------------------------------------------
__global__ __launch_bounds__(256) void k4_merge(
    const float* __restrict__ out_y, const float* __restrict__ mw,
    const float* __restrict__ mb, float* __restrict__ out)
{
    int idx = blockIdx.x * 256 + threadIdx.x;
    int dd = idx & 127;
    int p = idx >> 7;
    int i3 = p & 15, i2 = (p >> 4) & 15, i1 = (p >> 8) & 15;

    float accv = mb[0];
    #pragma unroll
    for (int k = 0; k < 12; k++) {
        int a1 = i1, a2 = i2, a3 = i3;
        if (k & 1) { a1 = 15 - i1; a2 = 15 - i2; a3 = 15 - i3; }
        int j1, j2, j3;
        switch (k >> 1) {
            case 0:  j1 = a1; j2 = a2; j3 = a3; break;
            case 1:  j1 = a1; j2 = a3; j3 = a2; break;
            case 2:  j1 = a3; j2 = a2; j3 = a1; break;
            case 3:  j1 = a3; j2 = a1; j3 = a2; break;
            case 4:  j1 = a2; j2 = a1; j3 = a3; break;
            default: j1 = a2; j2 = a3; j3 = a1; break;
        }
        int jb = (j1 << 8) | (j2 << 4) | j3;
        accv += mw[k] * out_y[(size_t)k * (DD * LL) + (jb >> 5) * LL
                              + ((jb & 31) << 7) + dd];
    }
    out[idx] = accv;
}

extern "C" void kernel_launch(void* const* d_in, const int* in_sizes, int n_in,
                              void* d_out, int out_size, void* d_ws, size_t ws_size,
                              hipStream_t stream) {
    const float* x      = (const float*)d_in[0];
    const float* Wp     = (const float*)d_in[1];
    const float* Wdt    = (const float*)d_in[2];
    const float* bias   = (const float*)d_in[3];
    const float* A_logs = (const float*)d_in[4];
    const float* Ds     = (const float*)d_in[5];
    const float* mw     = (const float*)d_in[6];
    const float* mb     = (const float*)d_in[7];
    float* out = (float*)d_out;

    float* ws   = (float*)d_ws;
    float* S_g  = ws;                                 // K*NC*D*N = 1572864
    float* dts  = S_g + (size_t)KK * NC * DD * NN;    // K*NC*D   =   98304
    float* oy   = dts + (size_t)KK * NC * DD;         // K*D*L    = 6291456
    float* xdbl = oy + (size_t)KK * DD * LL;          // 768*2816 = 2162688

    k1_proj_scanA<<<dim3(KK * NC), dim3(256), 0, stream>>>(
        x, Wp, Wdt, bias, A_logs, Ds, S_g, dts, oy, xdbl);
    k2_combine<<<dim3(KK * DD * NN / 256), dim3(256), 0, stream>>>(S_g, dts, A_logs);
    k3_corr<<<dim3(KK * NC), dim3(256), 0, stream>>>(Wdt, bias, A_logs, S_g, xdbl, oy);
    k4_merge<<<dim3(LL * DD / 256), dim3(256), 0, stream>>>(oy, mw, mb, out);
}

// Round 7
// 170.418 us; speedup vs baseline: 2.2770x; 1.0258x over previous
//
#include <hip/hip_runtime.h>

#define KK 12
#define LL 4096
#define DD 128
#define NN 16
#define RR 8
#define NC 128             // sub-chunks (2 per block)
#define LC 32              // sub-chunk length
#define XST 132            // x-tile / ybuf LDS stride (floats)
#define SDST 44            // x_dbl LDS row stride (floats)
#define XDBL_TILE (64 * SDST)   // 2816 floats per 64-l block tile

__device__ __forceinline__ int pos_of(int k, int l) {
    int o = k >> 1;
    int le = (k & 1) ? (4095 - l) : l;
    int t1 = le >> 8, t2 = (le >> 4) & 15, t3 = le & 15;
    switch (o) {
        case 0:  return (t1 << 8) | (t2 << 4) | t3;
        case 1:  return (t1 << 8) | (t3 << 4) | t2;
        case 2:  return (t3 << 8) | (t2 << 4) | t1;
        case 3:  return (t2 << 8) | (t3 << 4) | t1;
        case 4:  return (t2 << 8) | (t1 << 4) | t3;
        default: return (t3 << 8) | (t1 << 4) | t2;
    }
}

__device__ __forceinline__ float delta_row_z(const float* sdbl, int l,
                                             float4 w0, float4 w1, float bz) {
    const float4* dr = (const float4*)(sdbl + l * SDST);
    float4 r0 = dr[0], r1 = dr[1];
    return bz + w0.x * r0.x + w0.y * r0.y + w0.z * r0.z + w0.w * r0.w
              + w1.x * r1.x + w1.y * r1.y + w1.z * r1.z + w1.w * r1.w;
}

// Load -exp(A_logs[k][d][0..15]); check A[n] == (n+1)*A[0] structure.
__device__ __forceinline__ bool load_A16(const float* __restrict__ A_logs,
                                         int k, int d, float* A16) {
    const float4* ap = (const float4*)(A_logs + (size_t)(k * DD + d) * NN);
    #pragma unroll
    for (int q = 0; q < 4; q++) {
        float4 a4 = ap[q];
        A16[4*q+0] = -__expf(a4.x); A16[4*q+1] = -__expf(a4.y);
        A16[4*q+2] = -__expf(a4.z); A16[4*q+3] = -__expf(a4.w);
    }
    bool s = true;
    #pragma unroll
    for (int j = 1; j < 16; j++) {
        float m = (float)(j + 1);
        s = s && (fabsf(A16[j] - m * A16[0]) <= 1e-4f * m * fabsf(A16[0]));
    }
    return s;
}

template<bool S>
__device__ __forceinline__ void e16_from(float v, const float* A16, float* e) {
    if (S) {
        float q = __expf(v * A16[0]);
        e[0] = q;
        #pragma unroll
        for (int j = 1; j < 16; j++) e[j] = e[j - 1] * q;
    } else {
        #pragma unroll
        for (int j = 0; j < 16; j++) e[j] = __expf(v * A16[j]);
    }
}

// ---------------------------------------------------------------------------
// K1 scan body. Thread = (d, half); handles sub-chunk cc = 2c+half, rows
// rbase..rbase+31, all 16 states. y overwrites the consumed u slot in xs.
// ---------------------------------------------------------------------------
template<bool S>
__device__ __forceinline__ void scanA_body(
    float* xs, const float* sdbl, int k, int cc, int rbase, int d,
    const float* A16, float4 w0, float4 w1, float bz, float Dval,
    float* __restrict__ S_g, float* __restrict__ dtsum)
{
    float h[16];
    #pragma unroll
    for (int n = 0; n < 16; n++) h[n] = 0.0f;
    float dsum = 0.0f;

    #pragma unroll 4
    for (int i = 0; i < LC; i++) {
        int l = rbase + i;
        float z = delta_row_z(sdbl, l, w0, w1, bz);
        float E = __expf(-fabsf(z));
        float dt = fmaxf(z, 0.0f) + __logf(1.0f + E);
        float u = xs[l * XST + d];
        dsum += dt;
        float tu = dt * u;
        float e[16];
        e16_from<S>(dt, A16, e);
        const float4* bp = (const float4*)(&sdbl[l * SDST + 8]);
        float4 b0 = bp[0], b1 = bp[1], b2 = bp[2], b3 = bp[3];
        const float4* cp = (const float4*)(&sdbl[l * SDST + 24]);
        float4 c0 = cp[0], c1 = cp[1], c2 = cp[2], c3 = cp[3];
        h[0]  = e[0]  * h[0]  + tu * b0.x;  h[1]  = e[1]  * h[1]  + tu * b0.y;
        h[2]  = e[2]  * h[2]  + tu * b0.z;  h[3]  = e[3]  * h[3]  + tu * b0.w;
        h[4]  = e[4]  * h[4]  + tu * b1.x;  h[5]  = e[5]  * h[5]  + tu * b1.y;
        h[6]  = e[6]  * h[6]  + tu * b1.z;  h[7]  = e[7]  * h[7]  + tu * b1.w;
        h[8]  = e[8]  * h[8]  + tu * b2.x;  h[9]  = e[9]  * h[9]  + tu * b2.y;
        h[10] = e[10] * h[10] + tu * b2.z;  h[11] = e[11] * h[11] + tu * b2.w;
        h[12] = e[12] * h[12] + tu * b3.x;  h[13] = e[13] * h[13] + tu * b3.y;
        h[14] = e[14] * h[14] + tu * b3.z;  h[15] = e[15] * h[15] + tu * b3.w;
        float y = h[0]*c0.x + h[1]*c0.y + h[2]*c0.z + h[3]*c0.w
                + h[4]*c1.x + h[5]*c1.y + h[6]*c1.z + h[7]*c1.w
                + h[8]*c2.x + h[9]*c2.y + h[10]*c2.z + h[11]*c2.w
                + h[12]*c3.x + h[13]*c3.y + h[14]*c3.z + h[15]*c3.w;
        xs[l * XST + d] = y + Dval * u;
    }

    float4* sp = (float4*)(S_g + (((size_t)(k * NC + cc) * DD + d) * NN));
    sp[0] = make_float4(h[0],  h[1],  h[2],  h[3]);
    sp[1] = make_float4(h[4],  h[5],  h[6],  h[7]);
    sp[2] = make_float4(h[8],  h[9],  h[10], h[11]);
    sp[3] = make_float4(h[12], h[13], h[14], h[15]);
    dtsum[(k * NC + cc) * DD + d] = dsum;
}

// ---------------------------------------------------------------------------
// K1: proj GEMM + phase A local scan. Block = (k, 64-l tile), 256 threads.
// ---------------------------------------------------------------------------
__global__ __launch_bounds__(256, 3) void k1_proj_scanA(
    const float* __restrict__ x, const float* __restrict__ Wp,
    const float* __restrict__ Wdt, const float* __restrict__ bias,
    const float* __restrict__ A_logs, const float* __restrict__ Ds,
    float* __restrict__ S_g, float* __restrict__ dtsum,
    float* __restrict__ oy, float* __restrict__ xdbl)
{
    const int blk = blockIdx.x;
    const int k = blk >> 6;
    const int c = blk & 63;
    const int l0 = c * 64;
    const int t = threadIdx.x;

    __shared__ __align__(16) float xs[64 * XST];    // x-tile [l][d]; becomes y
    __shared__ __align__(16) float sdbl[64 * SDST]; // x_dbl [l][c]
    __shared__ int pos_s[64];

    if (t < 64) pos_s[t] = pos_of(k, l0 + t);
    __syncthreads();

    // ---- stage x tile (coalesced) ----
    {
        int lane32 = t & 31, rowi = t >> 5;
        #pragma unroll
        for (int p = 0; p < 8; p++) {
            int l = p * 8 + rowi;
            float4 v = *(const float4*)(x + (size_t)pos_s[l] * DD + lane32 * 4);
            *(float4*)(&xs[l * XST + lane32 * 4]) = v;
        }
    }
    __syncthreads();

    // ---- projection GEMM: wave cg computes 10 of 40 channels ----
    {
        int l = t & 63, cgch = t >> 6;
        float acc[10];
        #pragma unroll
        for (int j = 0; j < 10; j++) acc[j] = 0.0f;
        const float* wk = Wp + (size_t)(k * 40 + cgch * 10) * DD;
        for (int d4 = 0; d4 < DD; d4 += 4) {
            float4 xv = *(const float4*)(&xs[l * XST + d4]);
            #pragma unroll
            for (int j = 0; j < 10; j++) {
                const float* w = wk + j * DD + d4;   // wave-uniform -> s_load
                acc[j] += xv.x * w[0] + xv.y * w[1] + xv.z * w[2] + xv.w * w[3];
            }
        }
        #pragma unroll
        for (int j = 0; j < 10; j++) sdbl[l * SDST + cgch * 10 + j] = acc[j];
    }
    __syncthreads();

    // ---- spill x_dbl tile for K3 ----
    {
        const float4* s4 = (const float4*)sdbl;
        float4* g4 = (float4*)(xdbl + (size_t)blk * XDBL_TILE);
        for (int idx = t; idx < XDBL_TILE / 4; idx += 256) g4[idx] = s4[idx];
    }

    // ---- phase A scan: thread = (d, sub-chunk half) ----
    const int d = t & 127, half = t >> 7;
    const int cc = 2 * c + half, rbase = half * LC;
    float A16[16];
    bool structured = load_A16(A_logs, k, d, A16);
    const float4* wp4 = (const float4*)(Wdt + (size_t)(k * DD + d) * RR);
    const float4 w0 = wp4[0], w1 = wp4[1];
    const float bz = bias[k * DD + d];
    const float Dval = Ds[k * DD + d];

    if (structured)
        scanA_body<true>(xs, sdbl, k, cc, rbase, d, A16, w0, w1, bz, Dval,
                         S_g, dtsum);
    else
        scanA_body<false>(xs, sdbl, k, cc, rbase, d, A16, w0, w1, bz, Dval,
                          S_g, dtsum);

    // ---- transposed y store (reads only self-written slots; no barrier) ----
    {
        float* base = oy + ((size_t)(k * DD + d)) * LL + l0 + rbase;
        #pragma unroll
        for (int p = 0; p < 8; p++) {
            int j = p * 4;
            float4 v = make_float4(xs[(rbase + j + 0) * XST + d],
                                   xs[(rbase + j + 1) * XST + d],
                                   xs[(rbase + j + 2) * XST + d],
                                   xs[(rbase + j + 3) * XST + d]);
            *(float4*)(base + j) = v;
        }
    }
}

// ---------------------------------------------------------------------------
// K2: sequential combine across 128 sub-chunks; S <- true h0, in place.
// ---------------------------------------------------------------------------
__global__ __launch_bounds__(256) void k2_combine(
    float* __restrict__ S_g, const float* __restrict__ dtsum,
    const float* __restrict__ A_logs)
{
    int tid = blockIdx.x * 256 + threadIdx.x;   // k*2048 + d*16 + n
    int kk = tid >> 11, rem = tid & 2047, dd2 = rem >> 4;
    float Ac = -__expf(A_logs[tid]);
    float hh = 0.0f;
    #pragma unroll 8
    for (int c2 = 0; c2 < NC; c2++) {
        size_t base = ((size_t)(kk * NC + c2)) * 2048 + rem;
        float s = S_g[base];
        float dsv = dtsum[(kk * NC + c2) * DD + dd2];
        S_g[base] = hh;
        hh = s + __expf(dsv * Ac) * hh;
    }
}

// ---------------------------------------------------------------------------
// K3 body: y(l) += C(l) . (exp(Dsum_l * A) (.) h0). Serial chain = 1 add.
// ---------------------------------------------------------------------------
template<bool S>
__device__ __forceinline__ void corr_body(
    float* ybuf, const float* sdbl, int rbase, int d,
    const float* A16, const float* h0, float4 w0, float4 w1, float bz)
{
    float Dsum = 0.0f;
    #pragma unroll 4
    for (int i = 0; i < LC; i++) {
        int l = rbase + i;
        float z = delta_row_z(sdbl, l, w0, w1, bz);
        float E = __expf(-fabsf(z));
        float dt = fmaxf(z, 0.0f) + __logf(1.0f + E);
        Dsum += dt;
        float e[16];
        e16_from<S>(Dsum, A16, e);
        const float4* cp = (const float4*)(&sdbl[l * SDST + 24]);
        float4 c0 = cp[0], c1 = cp[1], c2 = cp[2], c3 = cp[3];
        float y = e[0]*h0[0]*c0.x + e[1]*h0[1]*c0.y + e[2]*h0[2]*c0.z + e[3]*h0[3]*c0.w
                + e[4]*h0[4]*c1.x + e[5]*h0[5]*c1.y + e[6]*h0[6]*c1.z + e[7]*h0[7]*c1.w
                + e[8]*h0[8]*c2.x + e[9]*h0[9]*c2.y + e[10]*h0[10]*c2.z + e[11]*h0[11]*c2.w
                + e[12]*h0[12]*c3.x + e[13]*h0[13]*c3.y + e[14]*h0[14]*c3.z + e[15]*h0[15]*c3.w;
        ybuf[l * XST + d] = y;
    }
}

__global__ __launch_bounds__(256, 3) void k3_corr(
    const float* __restrict__ Wdt, const float* __restrict__ bias,
    const float* __restrict__ A_logs, const float* __restrict__ S_g,
    const float* __restrict__ xdbl, float* __restrict__ oy)
{
    const int blk = blockIdx.x;
    const int k = blk >> 6;
    const int c = blk & 63;
    const int l0 = c * 64;
    const int t = threadIdx.x;

    __shared__ __align__(16) float sdbl[64 * SDST];
    __shared__ __align__(16) float ybuf[64 * XST];
    {
        const float4* g4 = (const float4*)(xdbl + (size_t)blk * XDBL_TILE);
        float4* s4 = (float4*)sdbl;
        for (int idx = t; idx < XDBL_TILE / 4; idx += 256) s4[idx] = g4[idx];
    }
    __syncthreads();

    const int d = t & 127, half = t >> 7;
    const int cc = 2 * c + half, rbase = half * LC;
    float A16[16];
    bool structured = load_A16(A_logs, k, d, A16);
    const float4* wp4 = (const float4*)(Wdt + (size_t)(k * DD + d) * RR);
    const float4 w0 = wp4[0], w1 = wp4[1];
    const float bz = bias[k * DD + d];

    float h0[16];
    if (cc != 0) {
        const float4* hp = (const float4*)(S_g + (((size_t)(k * NC + cc) * DD + d) * NN));
        float4 a = hp[0], b = hp[1], c4 = hp[2], e4 = hp[3];
        h0[0] = a.x;  h0[1] = a.y;  h0[2] = a.z;  h0[3] = a.w;
        h0[4] = b.x;  h0[5] = b.y;  h0[6] = b.z;  h0[7] = b.w;
        h0[8] = c4.x; h0[9] = c4.y; h0[10] = c4.z; h0[11] = c4.w;
        h0[12] = e4.x; h0[13] = e4.y; h0[14] = e4.z; h0[15] = e4.w;
    } else {
        #pragma unroll
        for (int n = 0; n < 16; n++) h0[n] = 0.0f;
    }

    if (structured)
        corr_body<true>(ybuf, sdbl, rbase, d, A16, h0, w0, w1, bz);
    else
        corr_body<false>(ybuf, sdbl, rbase, d, A16, h0, w0, w1, bz);

    // ---- transposed RMW of oy tile (self-written slots only) ----
    {
        float* base = oy + ((size_t)(k * DD + d)) * LL + l0 + rbase;
        #pragma unroll
        for (int p = 0; p < 8; p++) {
            int j = p * 4;
            float4 v = *(float4*)(base + j);
            v.x += ybuf[(rbase + j + 0) * XST + d];
            v.y += ybuf[(rbase + j + 1) * XST + d];
            v.z += ybuf[(rbase + j + 2) * XST + d];
            v.w += ybuf[(rbase + j + 3) * XST + d];
            *(float4*)(base + j) = v;
        }
    }
}

// ---------------------------------------------------------------------------
// K4: restore + merge (reference's (D,L)-flat reshape semantics).
// ---------------------------------------------------------------------------
__global__ __launch_bounds__(256) void k4_merge(
    const float* __restrict__ out_y, const float* __restrict__ mw,
    const float* __restrict__ mb, float* __restrict__ out)
{
    int idx = blockIdx.x * 256 + threadIdx.x;
    int dd = idx & 127;
    int p = idx >> 7;
    int i3 = p & 15, i2 = (p >> 4) & 15, i1 = (p >> 8) & 15;

    float accv = mb[0];
    #pragma unroll
    for (int k = 0; k < 12; k++) {
        int a1 = i1, a2 = i2, a3 = i3;
        if (k & 1) { a1 = 15 - i1; a2 = 15 - i2; a3 = 15 - i3; }
        int j1, j2, j3;
        switch (k >> 1) {
            case 0:  j1 = a1; j2 = a2; j3 = a3; break;
            case 1:  j1 = a1; j2 = a3; j3 = a2; break;
            case 2:  j1 = a3; j2 = a2; j3 = a1; break;
            case 3:  j1 = a3; j2 = a1; j3 = a2; break;
            case 4:  j1 = a2; j2 = a1; j3 = a3; break;
            default: j1 = a2; j2 = a3; j3 = a1; break;
        }
        int jb = (j1 << 8) | (j2 << 4) | j3;
        accv += mw[k] * out_y[(size_t)k * (DD * LL) + (jb >> 5) * LL
                              + ((jb & 31) << 7) + dd];
    }
    out[idx] = accv;
}

extern "C" void kernel_launch(void* const* d_in, const int* in_sizes, int n_in,
                              void* d_out, int out_size, void* d_ws, size_t ws_size,
                              hipStream_t stream) {
    const float* x      = (const float*)d_in[0];
    const float* Wp     = (const float*)d_in[1];
    const float* Wdt    = (const float*)d_in[2];
    const float* bias   = (const float*)d_in[3];
    const float* A_logs = (const float*)d_in[4];
    const float* Ds     = (const float*)d_in[5];
    const float* mw     = (const float*)d_in[6];
    const float* mb     = (const float*)d_in[7];
    float* out = (float*)d_out;

    float* ws   = (float*)d_ws;
    float* S_g  = ws;                                 // K*NC*D*N = 3145728
    float* dts  = S_g + (size_t)KK * NC * DD * NN;    // K*NC*D   =  196608
    float* oy   = dts + (size_t)KK * NC * DD;         // K*D*L    = 6291456
    float* xdbl = oy + (size_t)KK * DD * LL;          // 768*2816 = 2162688

    k1_proj_scanA<<<dim3(KK * 64), dim3(256), 0, stream>>>(
        x, Wp, Wdt, bias, A_logs, Ds, S_g, dts, oy, xdbl);
    k2_combine<<<dim3(KK * DD * NN / 256), dim3(256), 0, stream>>>(S_g, dts, A_logs);
    k3_corr<<<dim3(KK * 64), dim3(256), 0, stream>>>(Wdt, bias, A_logs, S_g, xdbl, oy);
    k4_merge<<<dim3(LL * DD / 256), dim3(256), 0, stream>>>(oy, mw, mb, out);
}

// Round 8
// 168.919 us; speedup vs baseline: 2.2972x; 1.0089x over previous
//
#include <hip/hip_runtime.h>

#define KK 12
#define LL 4096
#define DD 128
#define NN 16
#define RR 8
#define NC 128             // chunks (one per block)
#define LC 32              // chunk length = l-tile per block
#define XST 132            // x-tile / ybuf LDS stride (floats)
#define SDST 44            // x_dbl LDS row stride (floats)
#define XDBL_TILE (LC * SDST)   // 1408 floats per (k,chunk) tile

__device__ __forceinline__ int pos_of(int k, int l) {
    int o = k >> 1;
    int le = (k & 1) ? (4095 - l) : l;
    int t1 = le >> 8, t2 = (le >> 4) & 15, t3 = le & 15;
    switch (o) {
        case 0:  return (t1 << 8) | (t2 << 4) | t3;
        case 1:  return (t1 << 8) | (t3 << 4) | t2;
        case 2:  return (t3 << 8) | (t2 << 4) | t1;
        case 3:  return (t2 << 8) | (t3 << 4) | t1;
        case 4:  return (t2 << 8) | (t1 << 4) | t3;
        default: return (t3 << 8) | (t1 << 4) | t2;
    }
}

__device__ __forceinline__ float delta_row_z(const float* sdbl, int l,
                                             float4 w0, float4 w1, float bz) {
    const float4* dr = (const float4*)(sdbl + l * SDST);
    float4 r0 = dr[0], r1 = dr[1];
    return bz + w0.x * r0.x + w0.y * r0.y + w0.z * r0.z + w0.w * r0.w
              + w1.x * r1.x + w1.y * r1.y + w1.z * r1.z + w1.w * r1.w;
}

__device__ __forceinline__ bool load_A8(const float* __restrict__ A_logs,
                                        int k, int d, int n0, float* A8, float& A0) {
    const float4* ap = (const float4*)(A_logs + ((size_t)(k * DD + d) * NN + n0));
    float4 a0 = ap[0], a1 = ap[1];
    A8[0] = -__expf(a0.x); A8[1] = -__expf(a0.y);
    A8[2] = -__expf(a0.z); A8[3] = -__expf(a0.w);
    A8[4] = -__expf(a1.x); A8[5] = -__expf(a1.y);
    A8[6] = -__expf(a1.z); A8[7] = -__expf(a1.w);
    A0 = -__expf(A_logs[(size_t)(k * DD + d) * NN]);
    bool s = true;
    #pragma unroll
    for (int j = 0; j < 8; j++) {
        float m = (float)(n0 + j + 1);
        s = s && (fabsf(A8[j] - m * A0) <= 1e-4f * m * fabsf(A0));
    }
    return s;
}

// e[j] = q^(n0+j+1) with q = exp(v*A0) (structured), else exp(v*A8[j])
template<bool S>
__device__ __forceinline__ void e8_from(float v, float A0, const float* A8,
                                        int half, float* e) {
    if (S) {
        float q = __expf(v * A0);
        float q2 = q * q, q4 = q2 * q2, q8 = q4 * q4;
        e[0] = half ? q8 * q : q;
        #pragma unroll
        for (int j = 1; j < 8; j++) e[j] = e[j - 1] * q;
    } else {
        #pragma unroll
        for (int j = 0; j < 8; j++) e[j] = __expf(v * A8[j]);
    }
}

// ---------------------------------------------------------------------------
// K1 scan body. Thread = (d, n-half). u from xs[l][d]; y written back into
// the same LDS word (column-exclusive per pair, intra-wave -> race-free).
// ---------------------------------------------------------------------------
template<bool S>
__device__ __forceinline__ void scanA_body(
    float* xs, const float* sdbl, int k, int c,
    int d, int half, int n0, const float* A8, float A0,
    float4 w0, float4 w1, float bz, float Dval,
    float* __restrict__ S_g, float* __restrict__ dtsum)
{
    float h[8] = {0, 0, 0, 0, 0, 0, 0, 0};
    float dsum = 0.0f;

    #pragma unroll 4
    for (int i = 0; i < LC; i++) {
        float z = delta_row_z(sdbl, i, w0, w1, bz);
        float E = __expf(-fabsf(z));
        float dt = fmaxf(z, 0.0f) + __logf(1.0f + E);
        float u = xs[i * XST + d];
        dsum += dt;
        float tu = dt * u;
        float e[8];
        e8_from<S>(dt, A0, A8, half, e);
        const float4* bp = (const float4*)(&sdbl[i * SDST + 8 + n0]);
        float4 b0 = bp[0], b1 = bp[1];
        const float4* cp = (const float4*)(&sdbl[i * SDST + 24 + n0]);
        float4 c0 = cp[0], c1 = cp[1];
        h[0] = e[0] * h[0] + tu * b0.x;  h[1] = e[1] * h[1] + tu * b0.y;
        h[2] = e[2] * h[2] + tu * b0.z;  h[3] = e[3] * h[3] + tu * b0.w;
        h[4] = e[4] * h[4] + tu * b1.x;  h[5] = e[5] * h[5] + tu * b1.y;
        h[6] = e[6] * h[6] + tu * b1.z;  h[7] = e[7] * h[7] + tu * b1.w;
        float yp = h[0] * c0.x + h[1] * c0.y + h[2] * c0.z + h[3] * c0.w
                 + h[4] * c1.x + h[5] * c1.y + h[6] * c1.z + h[7] * c1.w;
        float yv = yp + __shfl_xor(yp, 1) + Dval * u;
        if (!half) xs[i * XST + d] = yv;
    }

    float4* sp = (float4*)(S_g + (((size_t)(k * NC + c) * DD + d) * NN + n0));
    sp[0] = make_float4(h[0], h[1], h[2], h[3]);
    sp[1] = make_float4(h[4], h[5], h[6], h[7]);
    if (!half) dtsum[(k * NC + c) * DD + d] = dsum;
}

// ---------------------------------------------------------------------------
// K1: proj GEMM + phase A local scan. Block = (k, 32-l chunk), 256 threads.
// LDS 22.7 KB -> ~7 blocks/CU.
// ---------------------------------------------------------------------------
__global__ __launch_bounds__(256, 4) void k1_proj_scanA(
    const float* __restrict__ x, const float* __restrict__ Wp,
    const float* __restrict__ Wdt, const float* __restrict__ bias,
    const float* __restrict__ A_logs, const float* __restrict__ Ds,
    float* __restrict__ S_g, float* __restrict__ dtsum,
    float* __restrict__ oy, float* __restrict__ xdbl)
{
    const int blk = blockIdx.x;
    const int k = blk >> 7;
    const int c = blk & 127;
    const int l0 = c * LC;
    const int t = threadIdx.x;

    __shared__ __align__(16) float xs[LC * XST];    // x-tile [l][d]; y overwrites
    __shared__ __align__(16) float sdbl[LC * SDST]; // x_dbl [l][c]
    __shared__ int pos_s[LC];

    if (t < LC) pos_s[t] = pos_of(k, l0 + t);
    __syncthreads();

    // ---- stage x tile: 4 passes x 8 rows x 32 lanes b128 (coalesced) ----
    {
        int lane32 = t & 31, rowi = t >> 5;
        #pragma unroll
        for (int p = 0; p < 4; p++) {
            int l = p * 8 + rowi;
            float4 v = *(const float4*)(x + (size_t)pos_s[l] * DD + lane32 * 4);
            *(float4*)(&xs[l * XST + lane32 * 4]) = v;
        }
    }
    __syncthreads();

    // ---- projection GEMM: group cg (of 8) computes 5 of 40 channels ----
    {
        int l = t & 31, cg = t >> 5;
        float acc[5];
        #pragma unroll
        for (int j = 0; j < 5; j++) acc[j] = 0.0f;
        const float* wk = Wp + (size_t)(k * 40 + cg * 5) * DD;
        for (int d4 = 0; d4 < DD; d4 += 4) {
            float4 xv = *(const float4*)(&xs[l * XST + d4]);
            #pragma unroll
            for (int j = 0; j < 5; j++) {
                const float* w = wk + j * DD + d4;   // wave-uniform -> s_load
                acc[j] += xv.x * w[0] + xv.y * w[1] + xv.z * w[2] + xv.w * w[3];
            }
        }
        #pragma unroll
        for (int j = 0; j < 5; j++) sdbl[l * SDST + cg * 5 + j] = acc[j];
    }
    __syncthreads();

    // ---- spill x_dbl tile for K3 ----
    {
        const float4* s4 = (const float4*)sdbl;
        float4* g4 = (float4*)(xdbl + (size_t)blk * XDBL_TILE);
        for (int idx = t; idx < XDBL_TILE / 4; idx += 256) g4[idx] = s4[idx];
    }

    // ---- phase A scan: thread = (d, n-half) ----
    const int d = t >> 1, half = t & 1, n0 = half * 8;
    float A8[8], A0;
    bool structured = load_A8(A_logs, k, d, n0, A8, A0);
    const float4* wp4 = (const float4*)(Wdt + (size_t)(k * DD + d) * RR);
    const float4 w0 = wp4[0], w1 = wp4[1];
    const float bz = bias[k * DD + d];
    const float Dval = Ds[k * DD + d];

    if (structured)
        scanA_body<true>(xs, sdbl, k, c, d, half, n0, A8, A0, w0, w1, bz,
                         Dval, S_g, dtsum);
    else
        scanA_body<false>(xs, sdbl, k, c, d, half, n0, A8, A0, w0, w1, bz,
                          Dval, S_g, dtsum);

    // ---- transposed y store (intra-wave pair data; no barrier needed) ----
    {
        float* base = oy + ((size_t)(k * DD + d)) * LL + l0 + half * 16;
        #pragma unroll
        for (int p = 0; p < 4; p++) {
            int j = p * 4;
            float4 v = make_float4(xs[(half * 16 + j + 0) * XST + d],
                                   xs[(half * 16 + j + 1) * XST + d],
                                   xs[(half * 16 + j + 2) * XST + d],
                                   xs[(half * 16 + j + 3) * XST + d]);
            *(float4*)(base + j) = v;
        }
    }
}

// ---------------------------------------------------------------------------
// K2: sequential combine across 128 chunks; S <- true h0, in place.
// ---------------------------------------------------------------------------
__global__ __launch_bounds__(256) void k2_combine(
    float* __restrict__ S_g, const float* __restrict__ dtsum,
    const float* __restrict__ A_logs)
{
    int tid = blockIdx.x * 256 + threadIdx.x;   // k*2048 + d*16 + n
    int kk = tid >> 11, rem = tid & 2047, dd2 = rem >> 4;
    float Ac = -__expf(A_logs[tid]);
    float hh = 0.0f;
    #pragma unroll 8
    for (int c2 = 0; c2 < NC; c2++) {
        size_t base = ((size_t)(kk * NC + c2)) * 2048 + rem;
        float s = S_g[base];
        float dsv = dtsum[(kk * NC + c2) * DD + dd2];
        S_g[base] = hh;
        hh = s + __expf(dsv * Ac) * hh;
    }
}

// ---------------------------------------------------------------------------
// K3 body: y(l) += C(l) . (exp(Dsum_l * A) (.) h0). Serial chain = 1 add.
// ---------------------------------------------------------------------------
template<bool S>
__device__ __forceinline__ void corr_body(
    float* ybuf, const float* sdbl, int d, int half, int n0,
    const float* A8, float A0, const float* h0, float4 w0, float4 w1, float bz)
{
    float Dsum = 0.0f;
    #pragma unroll 4
    for (int i = 0; i < LC; i++) {
        float z = delta_row_z(sdbl, i, w0, w1, bz);
        float E = __expf(-fabsf(z));
        float dt = fmaxf(z, 0.0f) + __logf(1.0f + E);
        Dsum += dt;
        float e[8];
        e8_from<S>(Dsum, A0, A8, half, e);
        const float4* cp = (const float4*)(&sdbl[i * SDST + 24 + n0]);
        float4 c0 = cp[0], c1 = cp[1];
        float yp = e[0]*h0[0]*c0.x + e[1]*h0[1]*c0.y + e[2]*h0[2]*c0.z + e[3]*h0[3]*c0.w
                 + e[4]*h0[4]*c1.x + e[5]*h0[5]*c1.y + e[6]*h0[6]*c1.z + e[7]*h0[7]*c1.w;
        float yv = yp + __shfl_xor(yp, 1);
        if (!half) ybuf[i * XST + d] = yv;
    }
}

__global__ __launch_bounds__(256, 4) void k3_corr(
    const float* __restrict__ Wdt, const float* __restrict__ bias,
    const float* __restrict__ A_logs, const float* __restrict__ S_g,
    const float* __restrict__ xdbl, float* __restrict__ oy)
{
    const int blk = blockIdx.x;
    const int k = blk >> 7;
    const int c = blk & 127;
    if (c == 0) return;                 // chunk 0 has h0 = 0
    const int l0 = c * LC;
    const int t = threadIdx.x;

    __shared__ __align__(16) float sdbl[LC * SDST];
    __shared__ __align__(16) float ybuf[LC * XST];
    {
        const float4* g4 = (const float4*)(xdbl + (size_t)blk * XDBL_TILE);
        float4* s4 = (float4*)sdbl;
        for (int idx = t; idx < XDBL_TILE / 4; idx += 256) s4[idx] = g4[idx];
    }
    __syncthreads();

    const int d = t >> 1, half = t & 1, n0 = half * 8;
    float A8[8], A0;
    bool structured = load_A8(A_logs, k, d, n0, A8, A0);
    const float4* wp4 = (const float4*)(Wdt + (size_t)(k * DD + d) * RR);
    const float4 w0 = wp4[0], w1 = wp4[1];
    const float bz = bias[k * DD + d];

    float h0[8];
    {
        const float4* hp = (const float4*)(S_g + (((size_t)(k * NC + c) * DD + d) * NN + n0));
        float4 h40 = hp[0], h41 = hp[1];
        h0[0] = h40.x; h0[1] = h40.y; h0[2] = h40.z; h0[3] = h40.w;
        h0[4] = h41.x; h0[5] = h41.y; h0[6] = h41.z; h0[7] = h41.w;
    }

    if (structured)
        corr_body<true>(ybuf, sdbl, d, half, n0, A8, A0, h0, w0, w1, bz);
    else
        corr_body<false>(ybuf, sdbl, d, half, n0, A8, A0, h0, w0, w1, bz);

    // ---- transposed RMW of oy tile (intra-wave pair data) ----
    {
        float* base = oy + ((size_t)(k * DD + d)) * LL + l0 + half * 16;
        #pragma unroll
        for (int p = 0; p < 4; p++) {
            int j = p * 4;
            float4 v = *(float4*)(base + j);
            v.x += ybuf[(half * 16 + j + 0) * XST + d];
            v.y += ybuf[(half * 16 + j + 1) * XST + d];
            v.z += ybuf[(half * 16 + j + 2) * XST + d];
            v.w += ybuf[(half * 16 + j + 3) * XST + d];
            *(float4*)(base + j) = v;
        }
    }
}

// ---------------------------------------------------------------------------
// K4: restore + merge (reference's (D,L)-flat reshape semantics).
// ---------------------------------------------------------------------------
__global__ __launch_bounds__(256) void k4_merge(
    const float* __restrict__ out_y, const float* __restrict__ mw,
    const float* __restrict__ mb, float* __restrict__ out)
{
    int idx = blockIdx.x * 256 + threadIdx.x;
    int dd = idx & 127;
    int p = idx >> 7;
    int i3 = p & 15, i2 = (p >> 4) & 15, i1 = (p >> 8) & 15;

    float accv = mb[0];
    #pragma unroll
    for (int k = 0; k < 12; k++) {
        int a1 = i1, a2 = i2, a3 = i3;
        if (k & 1) { a1 = 15 - i1; a2 = 15 - i2; a3 = 15 - i3; }
        int j1, j2, j3;
        switch (k >> 1) {
            case 0:  j1 = a1; j2 = a2; j3 = a3; break;
            case 1:  j1 = a1; j2 = a3; j3 = a2; break;
            case 2:  j1 = a3; j2 = a2; j3 = a1; break;
            case 3:  j1 = a3; j2 = a1; j3 = a2; break;
            case 4:  j1 = a2; j2 = a1; j3 = a3; break;
            default: j1 = a2; j2 = a3; j3 = a1; break;
        }
        int jb = (j1 << 8) | (j2 << 4) | j3;
        accv += mw[k] * out_y[(size_t)k * (DD * LL) + (jb >> 5) * LL
                              + ((jb & 31) << 7) + dd];
    }
    out[idx] = accv;
}

extern "C" void kernel_launch(void* const* d_in, const int* in_sizes, int n_in,
                              void* d_out, int out_size, void* d_ws, size_t ws_size,
                              hipStream_t stream) {
    const float* x      = (const float*)d_in[0];
    const float* Wp     = (const float*)d_in[1];
    const float* Wdt    = (const float*)d_in[2];
    const float* bias   = (const float*)d_in[3];
    const float* A_logs = (const float*)d_in[4];
    const float* Ds     = (const float*)d_in[5];
    const float* mw     = (const float*)d_in[6];
    const float* mb     = (const float*)d_in[7];
    float* out = (float*)d_out;

    float* ws   = (float*)d_ws;
    float* S_g  = ws;                                 // K*NC*D*N = 1572864
    float* dts  = S_g + (size_t)KK * NC * DD * NN;    // K*NC*D   =   98304
    float* oy   = dts + (size_t)KK * NC * DD;         // K*D*L    = 6291456
    float* xdbl = oy + (size_t)KK * DD * LL;          // 1536*1408 = 2162688

    k1_proj_scanA<<<dim3(KK * NC), dim3(256), 0, stream>>>(
        x, Wp, Wdt, bias, A_logs, Ds, S_g, dts, oy, xdbl);
    k2_combine<<<dim3(KK * DD * NN / 256), dim3(256), 0, stream>>>(S_g, dts, A_logs);
    k3_corr<<<dim3(KK * NC), dim3(256), 0, stream>>>(Wdt, bias, A_logs, S_g, xdbl, oy);
    k4_merge<<<dim3(LL * DD / 256), dim3(256), 0, stream>>>(oy, mw, mb, out);
}